// Round 2
// baseline (447.231 us; speedup 1.0000x reference)
//
#include <hip/hip_runtime.h>
#include <hip/hip_bf16.h>

typedef _Float16 half8_t __attribute__((ext_vector_type(8)));
typedef _Float16 half4_t __attribute__((ext_vector_type(4)));
typedef float    f32x4   __attribute__((ext_vector_type(4)));

#define CDIM 512
#define NHEAD 8
#define HD 64
#define NTOK 512
#define NWIN 64
#define TC 1536  // 3*C

// ws panel layout: per (local window w): 24 panels of 32768 halfs (65536 B)
//   panel (w*24 + 0*8 + h): Q  [n][d]   (later overwritten by attention output)
//   panel (w*24 + 1*8 + h): K  [n][d]
//   panel (w*24 + 2*8 + h): V^T [d][n]

__global__ void prep_weights(const float* __restrict__ wqkv, const float* __restrict__ wproj,
                             _Float16* __restrict__ wqkvT, _Float16* __restrict__ wprojT) {
  int idx = blockIdx.x * 256 + threadIdx.x;
  if (idx < TC * CDIM) {
    int c = idx / TC, o = idx % TC;
    wqkvT[(size_t)o * CDIM + c] = (_Float16)wqkv[idx];
  } else {
    int i2 = idx - TC * CDIM;
    if (i2 < CDIM * CDIM) {
      int c = i2 >> 9, o = i2 & 511;
      wprojT[(size_t)o * CDIM + c] = (_Float16)wproj[i2];
    }
  }
}

// ---------------- GEMM1: qkv = x @ Wqkv + b, write Q/K/[V^T] fp16 panels ----------------
__global__ __launch_bounds__(256) void gemm1_qkv(
    const float* __restrict__ x,       // chunk base: [nw*512][512] fp32
    const _Float16* __restrict__ wT,   // [1536][512] fp16
    const float* __restrict__ bias,    // [1536]
    _Float16* __restrict__ qkv) {
  __shared__ __align__(16) _Float16 As[128 * 40];  // pad stride 40 to spread banks
  __shared__ __align__(16) _Float16 Bs[128 * 40];
  const int tid = threadIdx.x;
  const int l = tid & 63;
  const int wid = tid >> 6;
  const int wr = wid >> 1, wc = wid & 1;
  const int lr = l & 15, lk8 = (l >> 4) * 8;
  const int m0 = blockIdx.x * 128;
  const int n0 = blockIdx.y * 128;

  f32x4 acc[4][4] = {};
  for (int ks = 0; ks < 16; ++ks) {
    const int k0 = ks * 32;
#pragma unroll
    for (int rep = 0; rep < 4; ++rep) {  // A: 128x32 fp32 -> fp16
      int row = rep * 32 + (tid >> 3);
      int col = (tid & 7) * 4;
      const float4 xv = *(const float4*)(x + (size_t)(m0 + row) * CDIM + k0 + col);
      half4_t hv = {(_Float16)xv.x, (_Float16)xv.y, (_Float16)xv.z, (_Float16)xv.w};
      *(half4_t*)(&As[row * 40 + col]) = hv;
    }
#pragma unroll
    for (int rep = 0; rep < 2; ++rep) {  // B: 128x32 fp16
      int row = rep * 64 + (tid >> 2);
      int col = (tid & 3) * 8;
      *(half8_t*)(&Bs[row * 40 + col]) =
          *(const half8_t*)(wT + (size_t)(n0 + row) * CDIM + k0 + col);
    }
    __syncthreads();
    half8_t a[4], b[4];
#pragma unroll
    for (int mt = 0; mt < 4; ++mt)
      a[mt] = *(const half8_t*)(&As[(wr * 64 + mt * 16 + lr) * 40 + lk8]);
#pragma unroll
    for (int nt = 0; nt < 4; ++nt)
      b[nt] = *(const half8_t*)(&Bs[(wc * 64 + nt * 16 + lr) * 40 + lk8]);
#pragma unroll
    for (int mt = 0; mt < 4; ++mt)
#pragma unroll
      for (int nt = 0; nt < 4; ++nt)
        acc[mt][nt] = __builtin_amdgcn_mfma_f32_16x16x32_f16(a[mt], b[nt], acc[mt][nt], 0, 0, 0);
    __syncthreads();
  }
  // epilogue: C/D layout col = l&15, row = (l>>4)*4 + reg  [m89-verified]
#pragma unroll
  for (int nt = 0; nt < 4; ++nt) {
    const int ch = n0 + wc * 64 + nt * 16 + lr;     // output channel 0..1535
    const int j = ch >> 9, h = (ch >> 6) & 7, d = ch & 63;
    const float bv = bias[ch];
#pragma unroll
    for (int mt = 0; mt < 4; ++mt) {
      const int row = m0 + wr * 64 + mt * 16 + ((l >> 4) << 2);  // +r, 4 consecutive
      const int wL = row >> 9, n = row & 511;
      _Float16* panel = qkv + ((size_t)(wL * 24 + j * 8 + h) << 15);
      if (j == 2) {  // V stored transposed [d][n]: 4 consecutive n -> one 8B store
        half4_t pk = {(_Float16)(acc[mt][nt][0] + bv), (_Float16)(acc[mt][nt][1] + bv),
                      (_Float16)(acc[mt][nt][2] + bv), (_Float16)(acc[mt][nt][3] + bv)};
        *(half4_t*)(panel + (size_t)d * 512 + n) = pk;
      } else {  // Q/K [n][d]
#pragma unroll
        for (int r = 0; r < 4; ++r)
          panel[(size_t)(n + r) * 64 + d] = (_Float16)(acc[mt][nt][r] + bv);
      }
    }
  }
}

// ---------------- attention v2: per (w,h,qhalf), 4 waves share LDS-staged K ----------------
// LDS: Ks = 256 K-rows (half panel), XOR-swizzled, 32KB; P = per-wave 64x32 fp16 swizzled, 16KB.
// 48KB total -> 3 blocks/CU. P is per-wave: no barrier in the kt loop.
__global__ __launch_bounds__(256) void attn_win(_Float16* __restrict__ qkv) {
  __shared__ __align__(16) _Float16 Ks[256 * 64];
  __shared__ __align__(16) _Float16 P[4 * 64 * 32];
  const int tid = threadIdx.x;
  const int l = tid & 63;
  const int wid = tid >> 6;
  const int lr = l & 15, lk8 = (l >> 4) * 8, lq4 = (l >> 4) * 4;
  const int b = blockIdx.x;
  const int qh = b & 1;
  const int h = (b >> 1) & 7;
  const int w = b >> 4;
  _Float16* Qp = qkv + ((size_t)(w * 24 + h) << 15);
  const _Float16* Kp = qkv + ((size_t)(w * 24 + 8 + h) << 15);
  const _Float16* Vp = qkv + ((size_t)(w * 24 + 16 + h) << 15);  // [d][n]
  const int q0 = qh * 256 + wid * 64;

  char* KsB = (char*)Ks;
  char* PwB = (char*)(P + wid * 2048);

  half8_t qf[4][2];  // Q rows in registers (A-fragments)
#pragma unroll
  for (int mt = 0; mt < 4; ++mt)
#pragma unroll
    for (int kc = 0; kc < 2; ++kc)
      qf[mt][kc] = *(const half8_t*)(Qp + (size_t)(q0 + mt * 16 + lr) * 64 + kc * 32 + lk8);

  f32x4 o[4][4] = {};
  float m[4][4], lsum[4][4];
#pragma unroll
  for (int mt = 0; mt < 4; ++mt)
#pragma unroll
    for (int r = 0; r < 4; ++r) { m[mt][r] = -1e30f; lsum[mt][r] = 0.f; }

  for (int half = 0; half < 2; ++half) {
    __syncthreads();  // all waves done reading Ks (previous half)
#pragma unroll
    for (int i = 0; i < 8; ++i) {  // stage 256 K-rows: 2048 x 16B chunks / 256 thr
      int c = i * 256 + tid;
      int row = c >> 3, d8 = c & 7;
      int byt = (row * 128 + d8 * 16) ^ ((row & 7) << 4);
      *(half8_t*)(KsB + byt) =
          *(const half8_t*)(Kp + (size_t)(half * 256 + row) * 64 + d8 * 8);
    }
    __syncthreads();
    for (int kt = 0; kt < 8; ++kt) {
      const int gkt = half * 8 + kt;
      f32x4 s[4][2] = {};
#pragma unroll
      for (int kc = 0; kc < 2; ++kc) {
        const int rk0 = kt * 32 + lr;
        const int rk1 = kt * 32 + 16 + lr;
        const int ck = (kc * 32 + lk8) * 2;
        half8_t bk0 = *(const half8_t*)(KsB + ((rk0 * 128 + ck) ^ ((rk0 & 7) << 4)));
        half8_t bk1 = *(const half8_t*)(KsB + ((rk1 * 128 + ck) ^ ((rk1 & 7) << 4)));
#pragma unroll
        for (int mt = 0; mt < 4; ++mt) {
          s[mt][0] = __builtin_amdgcn_mfma_f32_16x16x32_f16(qf[mt][kc], bk0, s[mt][0], 0, 0, 0);
          s[mt][1] = __builtin_amdgcn_mfma_f32_16x16x32_f16(qf[mt][kc], bk1, s[mt][1], 0, 0, 0);
        }
      }
      // online softmax; rows at (l>>4)*4+r within 16-lane key groups
#pragma unroll
      for (int mt = 0; mt < 4; ++mt) {
#pragma unroll
        for (int r = 0; r < 4; ++r) {
          float s0 = s[mt][0][r], s1 = s[mt][1][r];
          float mx = fmaxf(s0, s1);
#pragma unroll
          for (int off = 1; off < 16; off <<= 1) mx = fmaxf(mx, __shfl_xor(mx, off));
          float mn = fmaxf(m[mt][r], mx);
          float sc = __expf(m[mt][r] - mn);
          float p0 = __expf(s0 - mn), p1 = __expf(s1 - mn);
          float ps = p0 + p1;
#pragma unroll
          for (int off = 1; off < 16; off <<= 1) ps += __shfl_xor(ps, off);
          lsum[mt][r] = lsum[mt][r] * sc + ps;
          m[mt][r] = mn;
#pragma unroll
          for (int dt = 0; dt < 4; ++dt) o[mt][dt][r] *= sc;
          int qrow = mt * 16 + lq4 + r;
          int sw = (qrow & 7) << 4;
          *(_Float16*)(PwB + ((qrow * 64 + lr * 2) ^ sw)) = (_Float16)p0;
          *(_Float16*)(PwB + ((qrow * 64 + 32 + lr * 2) ^ sw)) = (_Float16)p1;
        }
      }
      // per-wave P: LDS ops are issue-ordered within a wave; no barrier needed
      half8_t pa[4], bv[4];
#pragma unroll
      for (int mt = 0; mt < 4; ++mt) {
        int pr = mt * 16 + lr;
        pa[mt] = *(const half8_t*)(PwB + ((pr * 64 + lk8 * 2) ^ ((pr & 7) << 4)));
      }
#pragma unroll
      for (int dt = 0; dt < 4; ++dt)  // V^T rows: 8 consecutive keys, contiguous
        bv[dt] = *(const half8_t*)(Vp + (size_t)(dt * 16 + lr) * 512 + gkt * 32 + lk8);
#pragma unroll
      for (int mt = 0; mt < 4; ++mt)
#pragma unroll
        for (int dt = 0; dt < 4; ++dt)
          o[mt][dt] = __builtin_amdgcn_mfma_f32_16x16x32_f16(pa[mt], bv[dt], o[mt][dt], 0, 0, 0);
    }
  }
  // normalize and write output IN-PLACE over own Q rows
#pragma unroll
  for (int mt = 0; mt < 4; ++mt) {
#pragma unroll
    for (int r = 0; r < 4; ++r) {
      float inv = 1.0f / lsum[mt][r];
      int qrow = q0 + mt * 16 + lq4 + r;
#pragma unroll
      for (int dt = 0; dt < 4; ++dt)
        Qp[(size_t)qrow * 64 + dt * 16 + lr] = (_Float16)(o[mt][dt][r] * inv);
    }
  }
}

// ---------------- GEMM2: out = attn_out @ Wproj + b (A-fragments direct from L2) ----------------
__global__ __launch_bounds__(256) void gemm2_proj(
    const _Float16* __restrict__ qkv,
    const _Float16* __restrict__ wpT,  // [512][512]
    const float* __restrict__ bias,    // [512]
    float* __restrict__ out) {         // chunk base [nw*512][512] fp32
  const int tid = threadIdx.x, l = tid & 63;
  const int wid = tid >> 6, wr = wid >> 1, wc = wid & 1;
  const int lr = l & 15, lk8 = (l >> 4) * 8;
  const int m0 = blockIdx.x * 128, n0 = blockIdx.y * 128;
  size_t aBase[4];
#pragma unroll
  for (int mt = 0; mt < 4; ++mt) {
    int row = m0 + wr * 64 + mt * 16 + lr;
    int wL = row >> 9, n = row & 511;
    aBase[mt] = ((size_t)(wL * 24) << 15) + (size_t)n * 64 + lk8;
  }
  size_t bBase[4];
#pragma unroll
  for (int nt = 0; nt < 4; ++nt)
    bBase[nt] = (size_t)(n0 + wc * 64 + nt * 16 + lr) * 512 + lk8;

  f32x4 acc[4][4] = {};
  for (int ks = 0; ks < 16; ++ks) {
    half8_t a[4], b[4];
    size_t aoff = (size_t)(ks >> 1) * 32768 + (size_t)(ks & 1) * 32;  // head panel + in-head k
#pragma unroll
    for (int mt = 0; mt < 4; ++mt) a[mt] = *(const half8_t*)(qkv + aBase[mt] + aoff);
#pragma unroll
    for (int nt = 0; nt < 4; ++nt) b[nt] = *(const half8_t*)(wpT + bBase[nt] + ks * 32);
#pragma unroll
    for (int mt = 0; mt < 4; ++mt)
#pragma unroll
      for (int nt = 0; nt < 4; ++nt)
        acc[mt][nt] = __builtin_amdgcn_mfma_f32_16x16x32_f16(a[mt], b[nt], acc[mt][nt], 0, 0, 0);
  }
#pragma unroll
  for (int nt = 0; nt < 4; ++nt) {
    int col = n0 + wc * 64 + nt * 16 + lr;
    float bv = bias[col];
#pragma unroll
    for (int mt = 0; mt < 4; ++mt) {
      int row = m0 + wr * 64 + mt * 16 + ((l >> 4) << 2);
#pragma unroll
      for (int r = 0; r < 4; ++r)
        out[(size_t)(row + r) * 512 + col] = acc[mt][nt][r] + bv;
    }
  }
}

extern "C" void kernel_launch(void* const* d_in, const int* in_sizes, int n_in,
                              void* d_out, int out_size, void* d_ws, size_t ws_size,
                              hipStream_t stream) {
  const float* x = (const float*)d_in[0];
  const float* wqkv = (const float*)d_in[1];
  const float* bqkv = (const float*)d_in[2];
  const float* wproj = (const float*)d_in[3];
  const float* bproj = (const float*)d_in[4];
  float* out = (float*)d_out;

  _Float16* wqkvT = (_Float16*)d_ws;
  _Float16* wprojT = wqkvT + (size_t)TC * CDIM;
  _Float16* qkvws = wprojT + (size_t)CDIM * CDIM;
  const size_t fixed = ((size_t)TC * CDIM + (size_t)CDIM * CDIM) * sizeof(_Float16);
  const size_t perwin = (size_t)24 * 32768 * sizeof(_Float16);
  int nw = 64;  // windows per chunk; shrink (pow2) to fit workspace
  while (nw > 1 && fixed + (size_t)nw * perwin > ws_size) nw >>= 1;

  prep_weights<<<dim3((TC * CDIM + CDIM * CDIM + 255) / 256), 256, 0, stream>>>(
      wqkv, wproj, wqkvT, wprojT);
  for (int wbase = 0; wbase < NWIN; wbase += nw) {
    const float* xc = x + (size_t)wbase * NTOK * CDIM;
    float* oc = out + (size_t)wbase * NTOK * CDIM;
    gemm1_qkv<<<dim3(nw * 4, 12), 256, 0, stream>>>(xc, wqkvT, bqkv, qkvws);
    attn_win<<<dim3(nw * 16), 256, 0, stream>>>(qkvws);
    gemm2_proj<<<dim3(nw * 4, 4), 256, 0, stream>>>(qkvws, wprojT, bproj, oc);
  }
}

// Round 3
// 262.214 us; speedup vs baseline: 1.7056x; 1.7056x over previous
//
#include <hip/hip_runtime.h>
#include <hip/hip_bf16.h>

typedef _Float16 half8_t __attribute__((ext_vector_type(8)));
typedef _Float16 half4_t __attribute__((ext_vector_type(4)));
typedef float    f32x4   __attribute__((ext_vector_type(4)));
typedef float    f32x16  __attribute__((ext_vector_type(16)));

#define CDIM 512
#define NHEAD 8
#define HD 64
#define NTOK 512
#define NWIN 64
#define TC 1536  // 3*C

// ws panel layout: per (local window w): 24 panels of 32768 halfs (65536 B)
//   panel (w*24 + 0*8 + h): Q  [n][d]   (later overwritten by attention output [n][d])
//   panel (w*24 + 1*8 + h): K  [n][d]
//   panel (w*24 + 2*8 + h): V key-permuted: [kg(32)][hh(2)][d(64)][e(8)]
//     where key n -> kg=n>>4, hh=(n>>2)&1, e=(n&3)+4*((n>>3)&1)
//     (so a PV A-fragment read lane(d=lane&31(+32), h2=lane>>5) is 16B contiguous,
//      and lane h2's own p-regs [r: key=(r&3)+8*(r>>2)+4*h2] are the B-frag in order)

__global__ void prep_weights(const float* __restrict__ wqkv, const float* __restrict__ wproj,
                             _Float16* __restrict__ wqkvT, _Float16* __restrict__ wprojT) {
  int idx = blockIdx.x * 256 + threadIdx.x;
  if (idx < TC * CDIM) {
    int c = idx / TC, o = idx % TC;
    wqkvT[(size_t)o * CDIM + c] = (_Float16)wqkv[idx];
  } else {
    int i2 = idx - TC * CDIM;
    if (i2 < CDIM * CDIM) {
      int c = i2 >> 9, o = i2 & 511;
      wprojT[(size_t)o * CDIM + c] = (_Float16)wproj[i2];
    }
  }
}

// ---------------- GEMM1: qkv = x @ Wqkv + b, write Q/K/[V-perm] fp16 panels ----------------
__global__ __launch_bounds__(256) void gemm1_qkv(
    const float* __restrict__ x,       // chunk base: [nw*512][512] fp32
    const _Float16* __restrict__ wT,   // [1536][512] fp16
    const float* __restrict__ bias,    // [1536]
    _Float16* __restrict__ qkv) {
  __shared__ __align__(16) _Float16 As[128 * 40];
  __shared__ __align__(16) _Float16 Bs[128 * 40];
  const int tid = threadIdx.x;
  const int l = tid & 63;
  const int wid = tid >> 6;
  const int wr = wid >> 1, wc = wid & 1;
  const int lr = l & 15, lk8 = (l >> 4) * 8;
  const int m0 = blockIdx.x * 128;
  const int n0 = blockIdx.y * 128;

  f32x4 acc[4][4] = {};
  for (int ks = 0; ks < 16; ++ks) {
    const int k0 = ks * 32;
#pragma unroll
    for (int rep = 0; rep < 4; ++rep) {  // A: 128x32 fp32 -> fp16
      int row = rep * 32 + (tid >> 3);
      int col = (tid & 7) * 4;
      const float4 xv = *(const float4*)(x + (size_t)(m0 + row) * CDIM + k0 + col);
      half4_t hv = {(_Float16)xv.x, (_Float16)xv.y, (_Float16)xv.z, (_Float16)xv.w};
      *(half4_t*)(&As[row * 40 + col]) = hv;
    }
#pragma unroll
    for (int rep = 0; rep < 2; ++rep) {  // B: 128x32 fp16
      int row = rep * 64 + (tid >> 2);
      int col = (tid & 3) * 8;
      *(half8_t*)(&Bs[row * 40 + col]) =
          *(const half8_t*)(wT + (size_t)(n0 + row) * CDIM + k0 + col);
    }
    __syncthreads();
    half8_t a[4], b[4];
#pragma unroll
    for (int mt = 0; mt < 4; ++mt)
      a[mt] = *(const half8_t*)(&As[(wr * 64 + mt * 16 + lr) * 40 + lk8]);
#pragma unroll
    for (int nt = 0; nt < 4; ++nt)
      b[nt] = *(const half8_t*)(&Bs[(wc * 64 + nt * 16 + lr) * 40 + lk8]);
#pragma unroll
    for (int mt = 0; mt < 4; ++mt)
#pragma unroll
      for (int nt = 0; nt < 4; ++nt)
        acc[mt][nt] = __builtin_amdgcn_mfma_f32_16x16x32_f16(a[mt], b[nt], acc[mt][nt], 0, 0, 0);
    __syncthreads();
  }
  // epilogue: C/D layout col = l&15, row = (l>>4)*4 + reg
#pragma unroll
  for (int nt = 0; nt < 4; ++nt) {
    const int ch = n0 + wc * 64 + nt * 16 + lr;     // output channel 0..1535
    const int j = ch >> 9, h = (ch >> 6) & 7, d = ch & 63;
    const float bv = bias[ch];
#pragma unroll
    for (int mt = 0; mt < 4; ++mt) {
      const int row = m0 + wr * 64 + mt * 16 + ((l >> 4) << 2);  // +r, 4 consecutive
      const int wL = row >> 9, n = row & 511;
      _Float16* panel = qkv + ((size_t)(wL * 24 + j * 8 + h) << 15);
      if (j == 2) {  // V key-permuted: 4 consecutive n -> 4 consecutive e -> one 8B store
        const int kg = n >> 4;
        const int hh = (n >> 2) & 1;
        const int e4 = (n & 8) >> 1;  // 4*((n>>3)&1)
        half4_t pk = {(_Float16)(acc[mt][nt][0] + bv), (_Float16)(acc[mt][nt][1] + bv),
                      (_Float16)(acc[mt][nt][2] + bv), (_Float16)(acc[mt][nt][3] + bv)};
        *(half4_t*)(panel + ((size_t)(kg * 2 + hh) * 64 + d) * 8 + e4) = pk;
      } else {  // Q/K [n][d]
#pragma unroll
        for (int r = 0; r < 4; ++r)
          panel[(size_t)(n + r) * 64 + d] = (_Float16)(acc[mt][nt][r] + bv);
      }
    }
  }
}

// ---------------- attention v3: swapped QK^T, lane-local softmax, zero LDS ----------------
// Block = 4 independent waves; wave owns 32 q-rows. mfma(A=K,B=Q) -> S^T[key][qrow]:
// qrow = lane&31, key = kt*32 + (r&3)+8*(r>>2)+4*(lane>>5) over 16 regs.
// PV: O^T[d][qrow] = mfma(A=Vperm, B=P); lane's p regs are the B-frag in storage order.
__global__ __launch_bounds__(256) void attn_win(_Float16* __restrict__ qkv) {
  const int tid = threadIdx.x;
  const int l = tid & 63;
  const int wid = tid >> 6;
  const int q32 = l & 31;
  const int h2 = l >> 5;
  const int b = blockIdx.x;
  const int qc = b & 3;
  const int h = (b >> 2) & 7;
  const int w = b >> 5;
  _Float16* Qp = qkv + ((size_t)(w * 24 + h) << 15);
  const _Float16* Kp = qkv + ((size_t)(w * 24 + 8 + h) << 15);
  const _Float16* Vp = qkv + ((size_t)(w * 24 + 16 + h) << 15);
  const int qrow = qc * 128 + wid * 32 + q32;

  half8_t qf[4];  // Q B-frags: k-slot = j*16 + h2*8 + e over head dim
#pragma unroll
  for (int j = 0; j < 4; ++j)
    qf[j] = *(const half8_t*)(Qp + (size_t)qrow * 64 + j * 16 + h2 * 8);

  f32x16 o0 = {}, o1 = {};  // O^T d-tiles 0/1: d = dt*32 + (r&3)+8*(r>>2)+4*h2
  float m_run = -1e30f, lsum = 0.f;

  for (int kt = 0; kt < 16; ++kt) {
    half8_t kf[4];  // K A-frags: row = kt*32+q32, k-slot = j*16 + h2*8 + e
#pragma unroll
    for (int j = 0; j < 4; ++j)
      kf[j] = *(const half8_t*)(Kp + (size_t)(kt * 32 + q32) * 64 + j * 16 + h2 * 8);
    f32x16 s = {};
#pragma unroll
    for (int j = 0; j < 4; ++j)
      s = __builtin_amdgcn_mfma_f32_32x32x16_f16(kf[j], qf[j], s, 0, 0, 0);

    // lane-local tile max (16 keys) + partner half (other 16 keys, same qrow)
    float tmax = s[0];
#pragma unroll
    for (int r = 1; r < 16; ++r) tmax = fmaxf(tmax, s[r]);
    tmax = fmaxf(tmax, __shfl_xor(tmax, 32));
    if (!__all(tmax <= m_run + 8.f)) {  // T13 defer-max: p bounded by e^8, fp16-safe
      float mNew = fmaxf(m_run, tmax);
      float sc = __expf(m_run - mNew);
      lsum *= sc;
#pragma unroll
      for (int r = 0; r < 16; ++r) { o0[r] *= sc; o1[r] *= sc; }
      m_run = mNew;
    }
    float p[16], tsum = 0.f;
#pragma unroll
    for (int r = 0; r < 16; ++r) { p[r] = __expf(s[r] - m_run); tsum += p[r]; }
    tsum += __shfl_xor(tsum, 32);
    lsum += tsum;

    half8_t pf0, pf1;  // B-frags for the two 16-key PV steps: own regs, in order
#pragma unroll
    for (int e = 0; e < 8; ++e) { pf0[e] = (_Float16)p[e]; pf1[e] = (_Float16)(p[8 + e]); }

    const _Float16* vb = Vp + (size_t)(kt * 4 + h2) * 512 + q32 * 8;
    half8_t vf;
    vf = *(const half8_t*)(vb);
    o0 = __builtin_amdgcn_mfma_f32_32x32x16_f16(vf, pf0, o0, 0, 0, 0);
    vf = *(const half8_t*)(vb + 256);
    o1 = __builtin_amdgcn_mfma_f32_32x32x16_f16(vf, pf0, o1, 0, 0, 0);
    vf = *(const half8_t*)(vb + 1024);
    o0 = __builtin_amdgcn_mfma_f32_32x32x16_f16(vf, pf1, o0, 0, 0, 0);
    vf = *(const half8_t*)(vb + 1280);
    o1 = __builtin_amdgcn_mfma_f32_32x32x16_f16(vf, pf1, o1, 0, 0, 0);
  }
  const float inv = 1.0f / lsum;
  // write O[qrow][d] in-place over Q panel; d = dt*32 + 8*rq + 4*h2 + i (reg = rq*4+i)
#pragma unroll
  for (int rq = 0; rq < 4; ++rq) {
    half4_t v0, v1;
#pragma unroll
    for (int i = 0; i < 4; ++i) {
      v0[i] = (_Float16)(o0[rq * 4 + i] * inv);
      v1[i] = (_Float16)(o1[rq * 4 + i] * inv);
    }
    *(half4_t*)(Qp + (size_t)qrow * 64 + 8 * rq + 4 * h2) = v0;
    *(half4_t*)(Qp + (size_t)qrow * 64 + 32 + 8 * rq + 4 * h2) = v1;
  }
}

// ---------------- GEMM2: out = attn_out @ Wproj + b (A-fragments direct from L2) ----------------
__global__ __launch_bounds__(256) void gemm2_proj(
    const _Float16* __restrict__ qkv,
    const _Float16* __restrict__ wpT,  // [512][512]
    const float* __restrict__ bias,    // [512]
    float* __restrict__ out) {         // chunk base [nw*512][512] fp32
  const int tid = threadIdx.x, l = tid & 63;
  const int wid = tid >> 6, wr = wid >> 1, wc = wid & 1;
  const int lr = l & 15, lk8 = (l >> 4) * 8;
  const int m0 = blockIdx.x * 128, n0 = blockIdx.y * 128;
  size_t aBase[4];
#pragma unroll
  for (int mt = 0; mt < 4; ++mt) {
    int row = m0 + wr * 64 + mt * 16 + lr;
    int wL = row >> 9, n = row & 511;
    aBase[mt] = ((size_t)(wL * 24) << 15) + (size_t)n * 64 + lk8;
  }
  size_t bBase[4];
#pragma unroll
  for (int nt = 0; nt < 4; ++nt)
    bBase[nt] = (size_t)(n0 + wc * 64 + nt * 16 + lr) * 512 + lk8;

  f32x4 acc[4][4] = {};
  for (int ks = 0; ks < 16; ++ks) {
    half8_t a[4], b[4];
    size_t aoff = (size_t)(ks >> 1) * 32768 + (size_t)(ks & 1) * 32;  // head panel + in-head k
#pragma unroll
    for (int mt = 0; mt < 4; ++mt) a[mt] = *(const half8_t*)(qkv + aBase[mt] + aoff);
#pragma unroll
    for (int nt = 0; nt < 4; ++nt) b[nt] = *(const half8_t*)(wpT + bBase[nt] + ks * 32);
#pragma unroll
    for (int mt = 0; mt < 4; ++mt)
#pragma unroll
      for (int nt = 0; nt < 4; ++nt)
        acc[mt][nt] = __builtin_amdgcn_mfma_f32_16x16x32_f16(a[mt], b[nt], acc[mt][nt], 0, 0, 0);
  }
#pragma unroll
  for (int nt = 0; nt < 4; ++nt) {
    int col = n0 + wc * 64 + nt * 16 + lr;
    float bv = bias[col];
#pragma unroll
    for (int mt = 0; mt < 4; ++mt) {
      int row = m0 + wr * 64 + mt * 16 + ((l >> 4) << 2);
#pragma unroll
      for (int r = 0; r < 4; ++r)
        out[(size_t)(row + r) * 512 + col] = acc[mt][nt][r] + bv;
    }
  }
}

extern "C" void kernel_launch(void* const* d_in, const int* in_sizes, int n_in,
                              void* d_out, int out_size, void* d_ws, size_t ws_size,
                              hipStream_t stream) {
  const float* x = (const float*)d_in[0];
  const float* wqkv = (const float*)d_in[1];
  const float* bqkv = (const float*)d_in[2];
  const float* wproj = (const float*)d_in[3];
  const float* bproj = (const float*)d_in[4];
  float* out = (float*)d_out;

  _Float16* wqkvT = (_Float16*)d_ws;
  _Float16* wprojT = wqkvT + (size_t)TC * CDIM;
  _Float16* qkvws = wprojT + (size_t)CDIM * CDIM;
  const size_t fixed = ((size_t)TC * CDIM + (size_t)CDIM * CDIM) * sizeof(_Float16);
  const size_t perwin = (size_t)24 * 32768 * sizeof(_Float16);
  int nw = 64;  // windows per chunk; shrink (pow2) to fit workspace
  while (nw > 1 && fixed + (size_t)nw * perwin > ws_size) nw >>= 1;

  prep_weights<<<dim3((TC * CDIM + CDIM * CDIM + 255) / 256), 256, 0, stream>>>(
      wqkv, wproj, wqkvT, wprojT);
  for (int wbase = 0; wbase < NWIN; wbase += nw) {
    const float* xc = x + (size_t)wbase * NTOK * CDIM;
    float* oc = out + (size_t)wbase * NTOK * CDIM;
    gemm1_qkv<<<dim3(nw * 4, 12), 256, 0, stream>>>(xc, wqkvT, bqkv, qkvws);
    attn_win<<<dim3(nw * 32), 256, 0, stream>>>(qkvws);
    gemm2_proj<<<dim3(nw * 4, 4), 256, 0, stream>>>(qkvws, wprojT, bproj, oc);
  }
}